// Round 1
// baseline (3050.332 us; speedup 1.0000x reference)
//
#include <hip/hip_runtime.h>
#include <hip/hip_bf16.h>

// Geometry (fixed by the problem): B=1, C=8, D=H=W=128.
constexpr int DD  = 128;
constexpr int HH  = 128;
constexpr int WW  = 128;
constexpr int HW2 = HH * WW;          // 16384
constexpr int DHW = DD * HH * WW;     // 2097152
constexpr int CIN = 8;

// ---------------------------------------------------------------------------
// Kernel 1: conv3d(x, w1) + bias + ReLU  (8 -> 8 channels, 3x3x3, SAME/zero pad)
// 4 voxels per thread along D (d0, d0+32, d0+64, d0+96) so each LDS weight
// broadcast feeds 4 FMAs.
// ---------------------------------------------------------------------------
__global__ __launch_bounds__(256) void k_conv1(
    const float* __restrict__ x, const float* __restrict__ w1,
    const float* __restrict__ b1, float* __restrict__ hb) {
  __shared__ float ws[8 * 27 * 8];  // [(ci*27+tap)*8 + co]
  __shared__ float bs[8];
  const int tid = threadIdx.x;
  for (int i = tid; i < 8 * 8 * 27; i += 256) {
    int co = i / 216;              // w1 layout: [co][ci][kd][kh][kw]
    int r  = i - co * 216;         // r = ci*27 + tap
    ws[r * 8 + co] = w1[i];
  }
  if (tid < 8) bs[tid] = b1[tid];
  __syncthreads();

  const int flat = blockIdx.x * 256 + tid;  // [0, DHW/4)
  const int d0 = flat >> 14;                // [0,32)
  const int rem = flat & (HW2 - 1);
  const int hh = rem >> 7;
  const int ww = rem & 127;

  // (dy,dx) clamped offsets + validity bits (shared by the 4 voxels)
  int off2[9];
  unsigned m2 = 0;
  {
    int j = 0;
#pragma unroll
    for (int dy = -1; dy <= 1; ++dy) {
      int yy = hh + dy; bool oky = (unsigned)yy < 128u; int yc = oky ? yy : hh;
#pragma unroll
      for (int dx = -1; dx <= 1; ++dx) {
        int xx = ww + dx; bool okx = (unsigned)xx < 128u; int xc = okx ? xx : ww;
        off2[j] = yc * WW + xc;
        if (oky && okx) m2 |= (1u << j);
        ++j;
      }
    }
  }

  float acc[8][4];
#pragma unroll
  for (int co = 0; co < 8; ++co)
#pragma unroll
    for (int v = 0; v < 4; ++v) acc[co][v] = bs[co];

  for (int ci = 0; ci < CIN; ++ci) {
    const float* base = x + (size_t)ci * DHW;
    for (int dz = -1; dz <= 1; ++dz) {
      int zoff[4]; bool okz[4];
#pragma unroll
      for (int v = 0; v < 4; ++v) {
        int zz = d0 + v * 32 + dz;
        okz[v] = (unsigned)zz < 128u;
        int zc = okz[v] ? zz : (d0 + v * 32);
        zoff[v] = zc * HW2;
      }
      const int tapbase = ci * 27 + (dz + 1) * 9;
#pragma unroll
      for (int j = 0; j < 9; ++j) {
        float val[4];
#pragma unroll
        for (int v = 0; v < 4; ++v) {
          float t = base[zoff[v] + off2[j]];
          val[v] = (okz[v] && ((m2 >> j) & 1u)) ? t : 0.0f;
        }
        const float* wrow = &ws[(tapbase + j) * 8];
#pragma unroll
        for (int co = 0; co < 8; ++co) {
          float wv = wrow[co];
#pragma unroll
          for (int v = 0; v < 4; ++v)
            acc[co][v] = fmaf(val[v], wv, acc[co][v]);
        }
      }
    }
  }

#pragma unroll
  for (int co = 0; co < 8; ++co) {
#pragma unroll
    for (int v = 0; v < 4; ++v) {
      int o = co * DHW + (d0 + v * 32) * HW2 + hh * WW + ww;
      hb[o] = fmaxf(acc[co][v], 0.0f);
    }
  }
}

// ---------------------------------------------------------------------------
// Kernel 2: conv3d(h, w2) (8 -> 27 channels) fused with L1 normalization over
// the 27 channels; writes normalized per-voxel weights as bf16.
// ---------------------------------------------------------------------------
__global__ __launch_bounds__(256) void k_conv2(
    const float* __restrict__ hb, const float* __restrict__ w2,
    __hip_bfloat16* __restrict__ wn) {
  __shared__ float ws[8 * 27 * 27];  // [(ci*27+tap)*27 + oc]
  const int tid = threadIdx.x;
  for (int i = tid; i < 27 * 8 * 27; i += 256) {
    int oc = i / 216;              // w2 layout: [oc][ci][kd][kh][kw]
    int r  = i - oc * 216;         // r = ci*27 + tap
    ws[r * 27 + oc] = w2[i];
  }
  __syncthreads();

  const int flat = blockIdx.x * 256 + tid;
  const int d0 = flat >> 14;
  const int rem = flat & (HW2 - 1);
  const int hh = rem >> 7;
  const int ww = rem & 127;

  int off2[9];
  unsigned m2 = 0;
  {
    int j = 0;
#pragma unroll
    for (int dy = -1; dy <= 1; ++dy) {
      int yy = hh + dy; bool oky = (unsigned)yy < 128u; int yc = oky ? yy : hh;
#pragma unroll
      for (int dx = -1; dx <= 1; ++dx) {
        int xx = ww + dx; bool okx = (unsigned)xx < 128u; int xc = okx ? xx : ww;
        off2[j] = yc * WW + xc;
        if (oky && okx) m2 |= (1u << j);
        ++j;
      }
    }
  }

  float acc[27][4];
#pragma unroll
  for (int oc = 0; oc < 27; ++oc)
#pragma unroll
    for (int v = 0; v < 4; ++v) acc[oc][v] = 0.0f;

  for (int ci = 0; ci < CIN; ++ci) {
    const float* base = hb + (size_t)ci * DHW;
    for (int dz = -1; dz <= 1; ++dz) {
      int zoff[4]; bool okz[4];
#pragma unroll
      for (int v = 0; v < 4; ++v) {
        int zz = d0 + v * 32 + dz;
        okz[v] = (unsigned)zz < 128u;
        int zc = okz[v] ? zz : (d0 + v * 32);
        zoff[v] = zc * HW2;
      }
      const int tapbase = ci * 27 + (dz + 1) * 9;
#pragma unroll
      for (int j = 0; j < 9; ++j) {
        float val[4];
#pragma unroll
        for (int v = 0; v < 4; ++v) {
          float t = base[zoff[v] + off2[j]];
          val[v] = (okz[v] && ((m2 >> j) & 1u)) ? t : 0.0f;
        }
        const float* wrow = &ws[(tapbase + j) * 27];
#pragma unroll
        for (int oc = 0; oc < 27; ++oc) {
          float wv = wrow[oc];
#pragma unroll
          for (int v = 0; v < 4; ++v)
            acc[oc][v] = fmaf(val[v], wv, acc[oc][v]);
        }
      }
    }
  }

#pragma unroll
  for (int v = 0; v < 4; ++v) {
    float n = 0.0f;
#pragma unroll
    for (int oc = 0; oc < 27; ++oc) n += fabsf(acc[oc][v]);
    float s = 1.0f / fmaxf(n, 1e-12f);
    const int o = (d0 + v * 32) * HW2 + hh * WW + ww;
#pragma unroll
    for (int oc = 0; oc < 27; ++oc)
      wn[(size_t)oc * DHW + o] = __float2bfloat16(acc[oc][v] * s);
  }
}

// ---------------------------------------------------------------------------
// Kernel 3: one adaptive 3x3x3 conv pass: out[c,p] = sum_t in[c, p+off(t)] * wn[t,p]
// ---------------------------------------------------------------------------
__global__ __launch_bounds__(256) void k_adapt(
    const float* __restrict__ in, const __hip_bfloat16* __restrict__ wn,
    float* __restrict__ out) {
  const int idx = blockIdx.x * 256 + threadIdx.x;  // [0, DHW)
  const int d = idx >> 14;
  const int rem = idx & (HW2 - 1);
  const int hh = rem >> 7;
  const int ww = rem & 127;

  int offs[27];
  unsigned mask = 0;
  {
    int t = 0;
#pragma unroll
    for (int dz = -1; dz <= 1; ++dz) {
      int zz = d + dz; bool okz = (unsigned)zz < 128u; int zc = okz ? zz : d;
#pragma unroll
      for (int dy = -1; dy <= 1; ++dy) {
        int yy = hh + dy; bool oky = (unsigned)yy < 128u; int yc = oky ? yy : hh;
#pragma unroll
        for (int dx = -1; dx <= 1; ++dx) {
          int xx = ww + dx; bool okx = (unsigned)xx < 128u; int xc = okx ? xx : ww;
          offs[t] = (zc * HH + yc) * WW + xc;
          if (okz && oky && okx) mask |= (1u << t);
          ++t;
        }
      }
    }
  }

  float wt[27];
#pragma unroll
  for (int t = 0; t < 27; ++t)
    wt[t] = __bfloat162float(wn[(size_t)t * DHW + idx]);

  for (int c = 0; c < 8; ++c) {
    const float* base = in + (size_t)c * DHW;
    float a = 0.0f;
#pragma unroll
    for (int t = 0; t < 27; ++t) {
      float v = base[offs[t]];
      v = ((mask >> t) & 1u) ? v : 0.0f;
      a = fmaf(v, wt[t], a);
    }
    out[(size_t)c * DHW + idx] = a;
  }
}

// ---------------------------------------------------------------------------
extern "C" void kernel_launch(void* const* d_in, const int* in_sizes, int n_in,
                              void* d_out, int out_size, void* d_ws, size_t ws_size,
                              hipStream_t stream) {
  const float* x  = (const float*)d_in[0];  // [1,8,128,128,128]
  const float* w1 = (const float*)d_in[1];  // [8,8,3,3,3]
  const float* b1 = (const float*)d_in[2];  // [8]
  const float* w2 = (const float*)d_in[3];  // [27,8,3,3,3]
  float* out = (float*)d_out;

  // Workspace layout: hb (64 MiB fp32) | wn (108 MiB bf16) | tb (64 MiB fp32)
  char* ws = (char*)d_ws;
  float* hb = (float*)ws;
  __hip_bfloat16* wn = (__hip_bfloat16*)(ws + (size_t)8 * DHW * 4);
  float* tb = (float*)(ws + (size_t)8 * DHW * 4 + (size_t)27 * DHW * 2);

  dim3 blk(256);
  k_conv1<<<DHW / 4 / 256, blk, 0, stream>>>(x, w1, b1, hb);
  k_conv2<<<DHW / 4 / 256, blk, 0, stream>>>(hb, w2, wn);
  k_adapt<<<DHW / 256, blk, 0, stream>>>(x,  wn, tb);
  k_adapt<<<DHW / 256, blk, 0, stream>>>(tb, wn, hb);
  k_adapt<<<DHW / 256, blk, 0, stream>>>(hb, wn, out);
}